// Round 10
// baseline (241.292 us; speedup 1.0000x reference)
//
#include <hip/hip_runtime.h>

#define DFEAT 128
#define NA 512           // fill blocks (edge chunks)
#define CELLW 20         // words per (bucket, ablock) cell: {cnt, 19 entries}
#define CAPAB 19         // payload entries per cell (lambda~8, P(>19)~1e-4)
#define MAXBKT 512       // static LDS sizing; requires N <= 131072
#define CAPH 2560        // per-HALF-bucket sorted-list capacity (lambda 2048, +11 sigma)
#define OVCAP 32768      // overflow list capacity (~20 expected)
#define CVTB 2048        // convert kernel blocks (grid-strided, no LDS)

typedef __attribute__((ext_vector_type(8))) short short8v;   // 8 bf16
typedef __attribute__((ext_vector_type(4))) float f32x4;     // MFMA C/D
typedef __attribute__((ext_vector_type(4))) unsigned short ushort4v;

__device__ __forceinline__ unsigned short f2bf(float f) {
    union { float f; unsigned u; } cv; cv.f = f;
    unsigned u = cv.u + 0x7fffu + ((cv.u >> 16) & 1u);   // RNE
    return (unsigned short)(u >> 16);
}
__device__ __forceinline__ float bf2f(unsigned short h) {
    union { unsigned u; float f; } cv; cv.u = ((unsigned)h) << 16; return cv.f;
}
__device__ __forceinline__ int load_idx(const void* eiv, int is64, size_t i) {
    return is64 ? (int)((const long long*)eiv)[i] : ((const int*)eiv)[i];
}

// ---------------------------------------------------------------------------
// fill v11: standalone LDS-binned edge partition (R7-proven structure).
// R9 post-mortem: fused prep was ~115us -- suspect the 42KB static LDS
// crippling the 12500 single-shot convert blocks (3 blocks/CU churn), so
// the 42KB now lives ONLY in these 512 blocks. Cell = {cnt, 19 x
// ((dst&255)<<17|src)}; bucket-major gbuf -> phase B reads 40KB dense spans.
// ---------------------------------------------------------------------------
__global__ __launch_bounds__(256) void fill_kernel(
        const void* __restrict__ eiv,
        unsigned* __restrict__ gbuf, int* __restrict__ ovcnt,
        int2* __restrict__ ov,
        int E, int N, int nbkt) {
    __shared__ unsigned lcnt[MAXBKT];
    __shared__ unsigned lbuf[MAXBKT * CELLW];
    const int b = blockIdx.x;

    const int* e32 = (const int*)eiv;
    int orsum = 0;
#pragma unroll
    for (int i = 0; i < 128; ++i) orsum |= e32[2 * i + 1];
    const int is64 = (orsum == 0);

    for (int w = threadIdx.x; w < nbkt; w += 256) lcnt[w] = 0;
    __syncthreads();

    const int chunk = (E + NA - 1) / NA;
    const int e0 = b * chunk;
    const int eEnd = min(e0 + chunk, E);
    for (int e = e0 + threadIdx.x; e < eEnd; e += 256) {
        int src = load_idx(eiv, is64, (size_t)e);
        int dst = load_idx(eiv, is64, (size_t)E + e);
        int bkt = dst >> 8;
        unsigned dl = (unsigned)(dst & 255);
        unsigned pos = atomicAdd(&lcnt[bkt], 1u);
        if (pos < CAPAB)
            lbuf[bkt * CELLW + 1 + pos] = (dl << 17) | (unsigned)src;
        else {
            int o = atomicAdd(ovcnt, 1);
            if (o < OVCAP) ov[o] = make_int2(dst, src);
        }
    }
    __syncthreads();
    for (int w = threadIdx.x; w < nbkt; w += 256)
        lbuf[w * CELLW] = min(lcnt[w], (unsigned)CAPAB);
    __syncthreads();
    const int tot = nbkt * CELLW;
    for (int w = threadIdx.x; w < tot; w += 256) {
        int k = w / CELLW, slot = w - k * CELLW;
        gbuf[((size_t)k * NA + b) * CELLW + slot] = lbuf[w];
    }
}

// ---------------------------------------------------------------------------
// convert v11: W->bf16^T (blocks 0..127, one shot) + x->bf16 (ALL blocks,
// grid-strided, ~6 float4/thread). ZERO LDS -> full occupancy streaming.
// ---------------------------------------------------------------------------
__global__ __launch_bounds__(256) void convert_kernel(
        const float* __restrict__ W1, const float* __restrict__ W2,
        unsigned short* __restrict__ w1bf, unsigned short* __restrict__ w2bf,
        const float* __restrict__ x, unsigned short* __restrict__ xb,
        int total4) {
    const int b = blockIdx.x;
    if (b < 128) {
        const float* W = (b < 64) ? W1 : W2;
        unsigned short* o = (b < 64) ? w1bf : w2bf;
        int idx = (b & 63) * 256 + threadIdx.x;   // idx = k*128+n
        int kk = idx >> 7, n = idx & 127;
        o[n * 128 + kk] = f2bf(W[idx]);
    }
    const int stride = CVTB * 256;
    for (int i = b * 256 + threadIdx.x; i < total4; i += stride) {
        float4 v = *(const float4*)&x[(size_t)i * 4];
        ushort4v o;
        o.x = f2bf(v.x); o.y = f2bf(v.y); o.z = f2bf(v.z); o.w = f2bf(v.w);
        *(ushort4v*)&xb[(size_t)i * 4] = o;
    }
}

// ---------------------------------------------------------------------------
// agg_mlp v10 (R9-proven, byte-identical): FUSED sort + gather + 2-layer
// MFMA MLP per (bucket, half). Gather is service-bound (~99us floor, R8);
// MLP overlaps it cross-block and h never round-trips through global.
// LDS: hlds 34.8KB + wbuf 34.8KB (union: sort scratch / W^T) -> 2 blocks/CU.
// ---------------------------------------------------------------------------
__global__ __launch_bounds__(512) void agg_mlp_kernel(
        const unsigned short* __restrict__ xb,
        const unsigned* __restrict__ gbuf,
        const int* __restrict__ ovcnt, const int2* __restrict__ ov,
        const float* __restrict__ epsp,
        const unsigned short* __restrict__ w1bf,
        const unsigned short* __restrict__ w2bf,
        const float* __restrict__ b1, const float* __restrict__ b2,
        float* __restrict__ out, int N) {
    __shared__ __align__(16) unsigned short hlds[128 * 136];  // h tile (bf16)
    __shared__ __align__(16) unsigned short wbuf[128 * 136];  // union: sort scratch / W^T
    int* cnt_s   = (int*)wbuf;         // [128]
    int* scanA   = cnt_s + 128;        // [128]
    int* start_s = scanA + 128;        // [129] (pad to 132)
    int* srcS    = start_s + 132;      // [CAPH] -> ends at 11792B < 34816B

    const int t = threadIdx.x;
    const int b = blockIdx.x >> 1;            // bucket
    const int h = blockIdx.x & 1;             // half: node slots h*128..h*128+127
    const int node0 = (b << 8) + (h << 7);

    // ---- load my cell (ablock = t), fully static unpack ----
    const uint4* cp = (const uint4*)&gbuf[((size_t)b * NA + t) * CELLW];
    uint4 c0 = cp[0], c1 = cp[1], c2 = cp[2], c3 = cp[3], c4 = cp[4];
    unsigned eb[CELLW];
    eb[0]  = c0.x; eb[1]  = c0.y; eb[2]  = c0.z; eb[3]  = c0.w;
    eb[4]  = c1.x; eb[5]  = c1.y; eb[6]  = c1.z; eb[7]  = c1.w;
    eb[8]  = c2.x; eb[9]  = c2.y; eb[10] = c2.z; eb[11] = c2.w;
    eb[12] = c3.x; eb[13] = c3.y; eb[14] = c3.z; eb[15] = c3.w;
    eb[16] = c4.x; eb[17] = c4.y; eb[18] = c4.z; eb[19] = c4.w;
    const int myc = (int)eb[0];               // <= CAPAB

    if (t < 128) cnt_s[t] = 0;
    __syncthreads();
#pragma unroll
    for (int k = 1; k <= CAPAB; ++k)
        if (k <= myc) {
            int dl = (int)(eb[k] >> 17);
            if ((dl >> 7) == h) atomicAdd(&cnt_s[dl & 127], 1);
        }
    __syncthreads();

    // ---- Hillis-Steele inclusive scan of cnt_s -> start_s (exclusive) ----
    if (t < 128) scanA[t] = cnt_s[t];
    __syncthreads();
    for (int off = 1; off < 128; off <<= 1) {
        int v = 0;
        if (t < 128) { v = scanA[t]; if (t >= off) v += scanA[t - off]; }
        __syncthreads();
        if (t < 128) scanA[t] = v;
        __syncthreads();
    }
    if (t < 128) start_s[t + 1] = scanA[t];
    if (t == 0) start_s[0] = 0;
    __syncthreads();
    if (t < 128) cnt_s[t] = start_s[t];       // cursor
    __syncthreads();

    // ---- scatter my half's entries into sorted per-node lists ----
#pragma unroll
    for (int k = 1; k <= CAPAB; ++k)
        if (k <= myc) {
            int dl = (int)(eb[k] >> 17);
            if ((dl >> 7) == h) {
                int pos = atomicAdd(&cnt_s[dl & 127], 1);
                if (pos < CAPH) srcS[pos] = (int)(eb[k] & 0x1FFFFu);
            }
        }
    __syncthreads();

    // ---- gather: 16 teams x 32 lanes over 128 nodes -> h into hlds ----
    {
        const int lane = t & 31;
        const int team = t >> 5;              // 0..15
        const int base = t & 32;              // ballot shift within 64-lane wave
        const int c = lane * 4;
        const float epsv = 1.0f + epsp[0];
        const int ovn = min(ovcnt[0], OVCAP);
        const int trips = (ovn + 31) >> 5;

        for (int jj = team; jj < 128; jj += 16) {
            int node = node0 + jj;
            if (node >= N) break;             // ascending: later jj also >= N
            int s = start_s[jj];
            int cnt = start_s[jj + 1] - s;

            ushort4v own = *(const ushort4v*)&xb[(size_t)node * DFEAT + c];
            float ax = epsv * bf2f(own.x), ay = epsv * bf2f(own.y);
            float az = epsv * bf2f(own.z), aw = epsv * bf2f(own.w);

            for (int i = 0; i < cnt; i += 16) {
                int rem = cnt - i;
                int sj[16];
#pragma unroll
                for (int q = 0; q < 16; ++q)
                    sj[q] = srcS[s + ((i + q < cnt) ? (i + q) : (cnt - 1))];
                ushort4v u[16];
#pragma unroll
                for (int q = 0; q < 16; ++q)
                    u[q] = *(const ushort4v*)&xb[(size_t)sj[q] * DFEAT + c];
#pragma unroll
                for (int q = 0; q < 16; ++q) {
                    if (rem > q) {
                        ax += bf2f(u[q].x); ay += bf2f(u[q].y);
                        az += bf2f(u[q].z); aw += bf2f(u[q].w);
                    }
                }
            }

            // overflow replay (tiny list, L2-resident)
            for (int tt = 0; tt < trips; ++tt) {
                int j = tt * 32 + lane;
                int2 eo = (j < ovn) ? ov[j] : make_int2(-1, 0);
                unsigned long long bm = __ballot(eo.x == node);
                unsigned m = (unsigned)(bm >> base);
                while (m) {
                    int l = __ffs(m) - 1; m &= m - 1;
                    int sv = __shfl(eo.y, base + l, 64);
                    ushort4v u = *(const ushort4v*)&xb[(size_t)sv * DFEAT + c];
                    ax += bf2f(u.x); ay += bf2f(u.y);
                    az += bf2f(u.z); aw += bf2f(u.w);
                }
            }

            ushort4v hv;
            hv.x = f2bf(ax); hv.y = f2bf(ay); hv.z = f2bf(az); hv.w = f2bf(aw);
            *(ushort4v*)&hlds[jj * 136 + c] = hv;   // h row stays in LDS
        }
    }
    __syncthreads();   // gather done; srcS dead -> wbuf becomes W^T tile

    // ---- MLP: 2 tiles (nodes 0-63, 64-127) x 4 waves, R4-proven layout ----
    for (int i = t; i < 128 * 16; i += 512) {
        int n = i >> 4, k0 = (i & 15) * 8;
        *(short8v*)&wbuf[n * 136 + k0] = *(const short8v*)&w1bf[n * 128 + k0];
    }
    __syncthreads();

    const int lane64 = t & 63;
    const int ws   = t >> 6;                  // 0..7
    const int tile = ws >> 2;                 // 0..1
    const int w    = ws & 3;                  // wave within tile
    const int l15  = lane64 & 15;
    const int quad = lane64 >> 4;
    const unsigned short* ha = &hlds[((tile << 6) + w * 16 + l15) * 136 + quad * 8];

    for (int layer = 0; layer < 2; ++layer) {
        if (layer == 1) {
            __syncthreads();
            for (int i = t; i < 128 * 16; i += 512) {
                int n = i >> 4, k0 = (i & 15) * 8;
                *(short8v*)&wbuf[n * 136 + k0] = *(const short8v*)&w2bf[n * 128 + k0];
            }
            __syncthreads();
        }

        f32x4 acc[8];
#pragma unroll
        for (int nt = 0; nt < 8; ++nt) acc[nt] = (f32x4){0.f, 0.f, 0.f, 0.f};

#pragma unroll
        for (int s = 0; s < 4; ++s) {
            short8v a = *(const short8v*)&ha[s * 32];
#pragma unroll
            for (int nt = 0; nt < 8; ++nt) {
                short8v bf = *(const short8v*)&wbuf[(nt * 16 + l15) * 136 + quad * 8 + s * 32];
                acc[nt] = __builtin_amdgcn_mfma_f32_16x16x32_bf16(a, bf, acc[nt], 0, 0, 0);
            }
        }

        const float* bias = layer ? b2 : b1;
        if (layer == 0) {
            __syncthreads();
#pragma unroll
            for (int nt = 0; nt < 8; ++nt) {
                float bv = bias[nt * 16 + l15];
#pragma unroll
                for (int r = 0; r < 4; ++r) {
                    float v = fmaxf(acc[nt][r] + bv, 0.f);
                    hlds[((tile << 6) + w * 16 + quad * 4 + r) * 136 + nt * 16 + l15] = f2bf(v);
                }
            }
        } else {
#pragma unroll
            for (int nt = 0; nt < 8; ++nt) {
                float bv = bias[nt * 16 + l15];
#pragma unroll
                for (int r = 0; r < 4; ++r) {
                    int node = node0 + (tile << 6) + w * 16 + quad * 4 + r;
                    if (node < N)
                        out[(size_t)node * DFEAT + nt * 16 + l15] = acc[nt][r] + bv;
                }
            }
        }
    }
}

// ===========================================================================
// Fallback (tiny ws): atomic scatter + fp32 vector MLP
// ===========================================================================
__global__ void detect_idx_kernel(const int* __restrict__ ei, int* __restrict__ flag) {
    if (threadIdx.x == 0 && blockIdx.x == 0) {
        int orsum = 0;
#pragma unroll
        for (int i = 0; i < 128; ++i) orsum |= ei[2 * i + 1];
        flag[0] = (orsum == 0) ? 1 : 0;
    }
}

__global__ __launch_bounds__(256) void scatter_kernel(
        const float* __restrict__ x, const void* __restrict__ eiv,
        const int* __restrict__ flag, float* __restrict__ agg, int E) {
    unsigned gid = blockIdx.x * 256u + threadIdx.x;
    unsigned e = gid >> 5;
    if (e >= (unsigned)E) return;
    int c = (gid & 31u) * 4;
    int is64 = flag[0];
    int src = load_idx(eiv, is64, (size_t)e);
    int dst = load_idx(eiv, is64, (size_t)E + e);
    float4 v = *(const float4*)&x[(size_t)src * DFEAT + c];
    float* p = &agg[(size_t)dst * DFEAT + c];
    unsafeAtomicAdd(p + 0, v.x);
    unsafeAtomicAdd(p + 1, v.y);
    unsafeAtomicAdd(p + 2, v.z);
    unsafeAtomicAdd(p + 3, v.w);
}

__global__ __launch_bounds__(256) void mlp_kernel(
        const float* __restrict__ xp,
        const float* __restrict__ W1, const float* __restrict__ b1,
        const float* __restrict__ W2, const float* __restrict__ b2,
        const float* __restrict__ epsp, float* __restrict__ out) {
    __shared__ float hs[32][DFEAT];
    __shared__ float Wc[64][DFEAT];

    const int tid = threadIdx.x;
    const int node0 = blockIdx.x * 32;
    const float epsv = 1.0f + epsp[0];

    for (int i = tid; i < 32 * (DFEAT / 4); i += 256) {
        int n = i >> 5;
        int c = (i & 31) * 4;
        size_t off = (size_t)(node0 + n) * DFEAT + c;
        float4 h = *(const float4*)&out[off];
        float4 xv = *(const float4*)&xp[off];
        h.x += epsv * xv.x; h.y += epsv * xv.y;
        h.z += epsv * xv.z; h.w += epsv * xv.w;
        *(float4*)&hs[n][c] = h;
    }

    const int og = (tid & 31) * 4;
    const int ng = (tid >> 5) * 4;

    for (int layer = 0; layer < 2; ++layer) {
        const float* W = layer ? W2 : W1;
        const float* b = layer ? b2 : b1;

        float acc[4][4];
#pragma unroll
        for (int j = 0; j < 4; ++j) {
            float bj = b[og + j];
#pragma unroll
            for (int i = 0; i < 4; ++i) acc[i][j] = bj;
        }

        for (int chunk = 0; chunk < 2; ++chunk) {
            __syncthreads();
            for (int i = tid; i < 64 * (DFEAT / 4); i += 256) {
                int r = i >> 5;
                int c = (i & 31) * 4;
                *(float4*)&Wc[r][c] =
                    *(const float4*)&W[(size_t)(chunk * 64 + r) * DFEAT + c];
            }
            __syncthreads();
            const int kb = chunk * 64;
            for (int k = 0; k < 64; k += 4) {
                float4 h4[4], w4[4];
#pragma unroll
                for (int i = 0; i < 4; ++i)
                    h4[i] = *(const float4*)&hs[ng + i][kb + k];
#pragma unroll
                for (int j = 0; j < 4; ++j)
                    w4[j] = *(const float4*)&Wc[k + j][og];
#pragma unroll
                for (int i = 0; i < 4; ++i) {
                    acc[i][0] += h4[i].x * w4[0].x + h4[i].y * w4[1].x
                               + h4[i].z * w4[2].x + h4[i].w * w4[3].x;
                    acc[i][1] += h4[i].x * w4[0].y + h4[i].y * w4[1].y
                               + h4[i].z * w4[2].y + h4[i].w * w4[3].y;
                    acc[i][2] += h4[i].x * w4[0].z + h4[i].y * w4[1].z
                               + h4[i].z * w4[2].z + h4[i].w * w4[3].z;
                    acc[i][3] += h4[i].x * w4[0].w + h4[i].y * w4[1].w
                               + h4[i].z * w4[2].w + h4[i].w * w4[3].w;
                }
            }
        }
        __syncthreads();

        if (layer == 0) {
#pragma unroll
            for (int i = 0; i < 4; ++i) {
                float4 r;
                r.x = fmaxf(acc[i][0], 0.0f);
                r.y = fmaxf(acc[i][1], 0.0f);
                r.z = fmaxf(acc[i][2], 0.0f);
                r.w = fmaxf(acc[i][3], 0.0f);
                *(float4*)&hs[ng + i][og] = r;
            }
        } else {
#pragma unroll
            for (int i = 0; i < 4; ++i) {
                float4 r;
                r.x = acc[i][0]; r.y = acc[i][1];
                r.z = acc[i][2]; r.w = acc[i][3];
                *(float4*)&out[(size_t)(node0 + ng + i) * DFEAT + og] = r;
            }
        }
    }
}

extern "C" void kernel_launch(void* const* d_in, const int* in_sizes, int n_in,
                              void* d_out, int out_size, void* d_ws, size_t ws_size,
                              hipStream_t stream) {
    const float* x   = (const float*)d_in[0];
    const void*  ei  = d_in[1];
    const float* W1  = (const float*)d_in[2];
    const float* b1  = (const float*)d_in[3];
    const float* W2  = (const float*)d_in[4];
    const float* b2  = (const float*)d_in[5];
    const float* eps = (const float*)d_in[6];
    float* out = (float*)d_out;

    const int N = in_sizes[0] / DFEAT;      // 100000
    const int E = in_sizes[1] / 2;          // 1600000
    const int total4 = N * (DFEAT / 4);     // 3.2M float4s in x
    const int nbkt = (N + 255) >> 8;        // 391 node-range buckets

    // ---- layout: [w1bf][w2bf][xb][ov][ovcnt][gbuf] ----  (~42MB)
    char* p = (char*)d_ws;
    unsigned short* w1bf = (unsigned short*)p;  p += 128 * 128 * 2;
    unsigned short* w2bf = (unsigned short*)p;  p += 128 * 128 * 2;
    unsigned short* xb = (unsigned short*)p;    p += (size_t)N * DFEAT * 2;
    int2* ov = (int2*)p;                        p += (size_t)OVCAP * 8;  // 256KB
    int* ovcnt = (int*)p;                       p += 64;
    unsigned* gbuf = (unsigned*)p;              p += (size_t)nbkt * NA * CELLW * 4; // 16MB
    size_t need = (size_t)(p - (char*)d_ws);

    if (ws_size >= need && nbkt <= MAXBKT) {
        hipMemsetAsync(ovcnt, 0, 64, stream);
        fill_kernel<<<NA, 256, 0, stream>>>(ei, gbuf, ovcnt, ov, E, N, nbkt);
        convert_kernel<<<CVTB, 256, 0, stream>>>(
            W1, W2, w1bf, w2bf, x, xb, total4);
        agg_mlp_kernel<<<nbkt * 2, 512, 0, stream>>>(
            xb, gbuf, ovcnt, ov, eps,
            w1bf, w2bf, b1, b2, out, N);
        return;
    }

    // ---- fallback: atomic scatter + fp32 MLP ----
    int* flag3 = (int*)d_ws;
    detect_idx_kernel<<<1, 64, 0, stream>>>((const int*)ei, flag3);
    hipMemsetAsync(d_out, 0, (size_t)out_size * sizeof(float), stream);
    unsigned total = (unsigned)E * 32u;
    scatter_kernel<<<(total + 255u) / 256u, 256, 0, stream>>>(x, ei, flag3, out, E);
    mlp_kernel<<<N / 32, 256, 0, stream>>>(x, W1, b1, W2, b2, eps, out);
}

// Round 11
// 234.851 us; speedup vs baseline: 1.0274x; 1.0274x over previous
//
#include <hip/hip_runtime.h>

#define DFEAT 128
#define NA 512           // fill blocks (edge chunks)
#define CELLW 20         // words per (bucket, ablock) cell: {cnt, 19 entries}
#define CAPAB 19         // payload entries per cell (lambda~8, P(>19)~1e-4)
#define MAXBKT 512       // static LDS sizing; requires N <= 131072
#define CAPH 2560        // per-HALF-bucket sorted-list capacity (lambda 2048, +11 sigma)
#define OVCAP 32768      // overflow list capacity (~20 expected)
#define CVTB 2048        // convert kernel blocks (grid-strided, no LDS)

typedef __attribute__((ext_vector_type(8))) short short8v;   // 8 bf16
typedef __attribute__((ext_vector_type(4))) float f32x4;     // MFMA C/D
typedef __attribute__((ext_vector_type(4))) unsigned short ushort4v;

__device__ __forceinline__ unsigned short f2bf(float f) {
    union { float f; unsigned u; } cv; cv.f = f;
    unsigned u = cv.u + 0x7fffu + ((cv.u >> 16) & 1u);   // RNE
    return (unsigned short)(u >> 16);
}
__device__ __forceinline__ float bf2f(unsigned short h) {
    union { unsigned u; float f; } cv; cv.u = ((unsigned)h) << 16; return cv.f;
}
__device__ __forceinline__ int load_idx(const void* eiv, int is64, size_t i) {
    return is64 ? (int)((const long long*)eiv)[i] : ((const int*)eiv)[i];
}

// ---------------------------------------------------------------------------
// fill v12: LDS-binned edge partition, branch-hoisted edge loads.
// 11 rounds of evidence: the front end cost ~95-125us in EVERY structure
// (global-atomic, LDS-binned, fused, split) while its streaming traffic
// models at ~25us. The one shared line was load_idx's per-element runtime
// is64 branch -- it defeats load pipelining. v12 hoists the branch to two
// clean unrolled loops and widens blocks to 512 thr (4 waves/SIMD).
// Cell = {cnt, 19 x ((dst&255)<<17|src)}; bucket-major gbuf.
// ---------------------------------------------------------------------------
__global__ __launch_bounds__(512) void fill_kernel(
        const void* __restrict__ eiv,
        unsigned* __restrict__ gbuf, int* __restrict__ ovcnt,
        int2* __restrict__ ov,
        int E, int N, int nbkt) {
    __shared__ unsigned lcnt[MAXBKT];
    __shared__ unsigned lbuf[MAXBKT * CELLW];
    const int b = blockIdx.x;
    const int t = threadIdx.x;

    const int* e32 = (const int*)eiv;
    int orsum = 0;
#pragma unroll
    for (int i = 0; i < 128; ++i) orsum |= e32[2 * i + 1];
    const int is64 = (orsum == 0);

    for (int w = t; w < nbkt; w += 512) lcnt[w] = 0;
    __syncthreads();

    const int chunk = (E + NA - 1) / NA;
    const int e0 = b * chunk;
    const int eEnd = min(e0 + chunk, E);

    if (is64) {
        const long long* e64 = (const long long*)eiv;
#pragma unroll 4
        for (int e = e0 + t; e < eEnd; e += 512) {
            int src = (int)e64[e];
            int dst = (int)e64[(size_t)E + e];
            int bkt = dst >> 8;
            unsigned dl = (unsigned)(dst & 255);
            unsigned pos = atomicAdd(&lcnt[bkt], 1u);
            if (pos < CAPAB)
                lbuf[bkt * CELLW + 1 + pos] = (dl << 17) | (unsigned)src;
            else {
                int o = atomicAdd(ovcnt, 1);
                if (o < OVCAP) ov[o] = make_int2(dst, src);
            }
        }
    } else {
#pragma unroll 4
        for (int e = e0 + t; e < eEnd; e += 512) {
            int src = e32[e];
            int dst = e32[(size_t)E + e];
            int bkt = dst >> 8;
            unsigned dl = (unsigned)(dst & 255);
            unsigned pos = atomicAdd(&lcnt[bkt], 1u);
            if (pos < CAPAB)
                lbuf[bkt * CELLW + 1 + pos] = (dl << 17) | (unsigned)src;
            else {
                int o = atomicAdd(ovcnt, 1);
                if (o < OVCAP) ov[o] = make_int2(dst, src);
            }
        }
    }
    __syncthreads();
    for (int w = t; w < nbkt; w += 512)
        lbuf[w * CELLW] = min(lcnt[w], (unsigned)CAPAB);
    __syncthreads();
    const int tot = nbkt * CELLW;
    for (int w = t; w < tot; w += 512) {
        int k = w / CELLW, slot = w - k * CELLW;
        gbuf[((size_t)k * NA + b) * CELLW + slot] = lbuf[w];
    }
}

// ---------------------------------------------------------------------------
// convert v11 (unchanged): W->bf16^T (blocks 0..127) + x->bf16 (all blocks,
// grid-strided float4). Zero LDS -> full-occupancy streaming.
// ---------------------------------------------------------------------------
__global__ __launch_bounds__(256) void convert_kernel(
        const float* __restrict__ W1, const float* __restrict__ W2,
        unsigned short* __restrict__ w1bf, unsigned short* __restrict__ w2bf,
        const float* __restrict__ x, unsigned short* __restrict__ xb,
        int total4) {
    const int b = blockIdx.x;
    if (b < 128) {
        const float* W = (b < 64) ? W1 : W2;
        unsigned short* o = (b < 64) ? w1bf : w2bf;
        int idx = (b & 63) * 256 + threadIdx.x;   // idx = k*128+n
        int kk = idx >> 7, n = idx & 127;
        o[n * 128 + kk] = f2bf(W[idx]);
    }
    const int stride = CVTB * 256;
    for (int i = b * 256 + threadIdx.x; i < total4; i += stride) {
        float4 v = *(const float4*)&x[(size_t)i * 4];
        ushort4v o;
        o.x = f2bf(v.x); o.y = f2bf(v.y); o.z = f2bf(v.z); o.w = f2bf(v.w);
        *(ushort4v*)&xb[(size_t)i * 4] = o;
    }
}

// ---------------------------------------------------------------------------
// agg_mlp v10 (R9/R10-proven, byte-identical): FUSED sort + gather + 2-layer
// MFMA MLP per (bucket, half). Gather is service-bound (~115us incl. MLP);
// h never round-trips through global. LDS: hlds 34.8KB + wbuf 34.8KB
// (union: sort scratch / W^T) -> 2 blocks/CU.
// ---------------------------------------------------------------------------
__global__ __launch_bounds__(512) void agg_mlp_kernel(
        const unsigned short* __restrict__ xb,
        const unsigned* __restrict__ gbuf,
        const int* __restrict__ ovcnt, const int2* __restrict__ ov,
        const float* __restrict__ epsp,
        const unsigned short* __restrict__ w1bf,
        const unsigned short* __restrict__ w2bf,
        const float* __restrict__ b1, const float* __restrict__ b2,
        float* __restrict__ out, int N) {
    __shared__ __align__(16) unsigned short hlds[128 * 136];  // h tile (bf16)
    __shared__ __align__(16) unsigned short wbuf[128 * 136];  // union: sort scratch / W^T
    int* cnt_s   = (int*)wbuf;         // [128]
    int* scanA   = cnt_s + 128;        // [128]
    int* start_s = scanA + 128;        // [129] (pad to 132)
    int* srcS    = start_s + 132;      // [CAPH] -> ends at 11792B < 34816B

    const int t = threadIdx.x;
    const int b = blockIdx.x >> 1;            // bucket
    const int h = blockIdx.x & 1;             // half: node slots h*128..h*128+127
    const int node0 = (b << 8) + (h << 7);

    // ---- load my cell (ablock = t), fully static unpack ----
    const uint4* cp = (const uint4*)&gbuf[((size_t)b * NA + t) * CELLW];
    uint4 c0 = cp[0], c1 = cp[1], c2 = cp[2], c3 = cp[3], c4 = cp[4];
    unsigned eb[CELLW];
    eb[0]  = c0.x; eb[1]  = c0.y; eb[2]  = c0.z; eb[3]  = c0.w;
    eb[4]  = c1.x; eb[5]  = c1.y; eb[6]  = c1.z; eb[7]  = c1.w;
    eb[8]  = c2.x; eb[9]  = c2.y; eb[10] = c2.z; eb[11] = c2.w;
    eb[12] = c3.x; eb[13] = c3.y; eb[14] = c3.z; eb[15] = c3.w;
    eb[16] = c4.x; eb[17] = c4.y; eb[18] = c4.z; eb[19] = c4.w;
    const int myc = (int)eb[0];               // <= CAPAB

    if (t < 128) cnt_s[t] = 0;
    __syncthreads();
#pragma unroll
    for (int k = 1; k <= CAPAB; ++k)
        if (k <= myc) {
            int dl = (int)(eb[k] >> 17);
            if ((dl >> 7) == h) atomicAdd(&cnt_s[dl & 127], 1);
        }
    __syncthreads();

    // ---- Hillis-Steele inclusive scan of cnt_s -> start_s (exclusive) ----
    if (t < 128) scanA[t] = cnt_s[t];
    __syncthreads();
    for (int off = 1; off < 128; off <<= 1) {
        int v = 0;
        if (t < 128) { v = scanA[t]; if (t >= off) v += scanA[t - off]; }
        __syncthreads();
        if (t < 128) scanA[t] = v;
        __syncthreads();
    }
    if (t < 128) start_s[t + 1] = scanA[t];
    if (t == 0) start_s[0] = 0;
    __syncthreads();
    if (t < 128) cnt_s[t] = start_s[t];       // cursor
    __syncthreads();

    // ---- scatter my half's entries into sorted per-node lists ----
#pragma unroll
    for (int k = 1; k <= CAPAB; ++k)
        if (k <= myc) {
            int dl = (int)(eb[k] >> 17);
            if ((dl >> 7) == h) {
                int pos = atomicAdd(&cnt_s[dl & 127], 1);
                if (pos < CAPH) srcS[pos] = (int)(eb[k] & 0x1FFFFu);
            }
        }
    __syncthreads();

    // ---- gather: 16 teams x 32 lanes over 128 nodes -> h into hlds ----
    {
        const int lane = t & 31;
        const int team = t >> 5;              // 0..15
        const int base = t & 32;              // ballot shift within 64-lane wave
        const int c = lane * 4;
        const float epsv = 1.0f + epsp[0];
        const int ovn = min(ovcnt[0], OVCAP);
        const int trips = (ovn + 31) >> 5;

        for (int jj = team; jj < 128; jj += 16) {
            int node = node0 + jj;
            if (node >= N) break;             // ascending: later jj also >= N
            int s = start_s[jj];
            int cnt = start_s[jj + 1] - s;

            ushort4v own = *(const ushort4v*)&xb[(size_t)node * DFEAT + c];
            float ax = epsv * bf2f(own.x), ay = epsv * bf2f(own.y);
            float az = epsv * bf2f(own.z), aw = epsv * bf2f(own.w);

            for (int i = 0; i < cnt; i += 16) {
                int rem = cnt - i;
                int sj[16];
#pragma unroll
                for (int q = 0; q < 16; ++q)
                    sj[q] = srcS[s + ((i + q < cnt) ? (i + q) : (cnt - 1))];
                ushort4v u[16];
#pragma unroll
                for (int q = 0; q < 16; ++q)
                    u[q] = *(const ushort4v*)&xb[(size_t)sj[q] * DFEAT + c];
#pragma unroll
                for (int q = 0; q < 16; ++q) {
                    if (rem > q) {
                        ax += bf2f(u[q].x); ay += bf2f(u[q].y);
                        az += bf2f(u[q].z); aw += bf2f(u[q].w);
                    }
                }
            }

            // overflow replay (tiny list, L2-resident)
            for (int tt = 0; tt < trips; ++tt) {
                int j = tt * 32 + lane;
                int2 eo = (j < ovn) ? ov[j] : make_int2(-1, 0);
                unsigned long long bm = __ballot(eo.x == node);
                unsigned m = (unsigned)(bm >> base);
                while (m) {
                    int l = __ffs(m) - 1; m &= m - 1;
                    int sv = __shfl(eo.y, base + l, 64);
                    ushort4v u = *(const ushort4v*)&xb[(size_t)sv * DFEAT + c];
                    ax += bf2f(u.x); ay += bf2f(u.y);
                    az += bf2f(u.z); aw += bf2f(u.w);
                }
            }

            ushort4v hv;
            hv.x = f2bf(ax); hv.y = f2bf(ay); hv.z = f2bf(az); hv.w = f2bf(aw);
            *(ushort4v*)&hlds[jj * 136 + c] = hv;   // h row stays in LDS
        }
    }
    __syncthreads();   // gather done; srcS dead -> wbuf becomes W^T tile

    // ---- MLP: 2 tiles (nodes 0-63, 64-127) x 4 waves, R4-proven layout ----
    for (int i = t; i < 128 * 16; i += 512) {
        int n = i >> 4, k0 = (i & 15) * 8;
        *(short8v*)&wbuf[n * 136 + k0] = *(const short8v*)&w1bf[n * 128 + k0];
    }
    __syncthreads();

    const int lane64 = t & 63;
    const int ws   = t >> 6;                  // 0..7
    const int tile = ws >> 2;                 // 0..1
    const int w    = ws & 3;                  // wave within tile
    const int l15  = lane64 & 15;
    const int quad = lane64 >> 4;
    const unsigned short* ha = &hlds[((tile << 6) + w * 16 + l15) * 136 + quad * 8];

    for (int layer = 0; layer < 2; ++layer) {
        if (layer == 1) {
            __syncthreads();
            for (int i = t; i < 128 * 16; i += 512) {
                int n = i >> 4, k0 = (i & 15) * 8;
                *(short8v*)&wbuf[n * 136 + k0] = *(const short8v*)&w2bf[n * 128 + k0];
            }
            __syncthreads();
        }

        f32x4 acc[8];
#pragma unroll
        for (int nt = 0; nt < 8; ++nt) acc[nt] = (f32x4){0.f, 0.f, 0.f, 0.f};

#pragma unroll
        for (int s = 0; s < 4; ++s) {
            short8v a = *(const short8v*)&ha[s * 32];
#pragma unroll
            for (int nt = 0; nt < 8; ++nt) {
                short8v bf = *(const short8v*)&wbuf[(nt * 16 + l15) * 136 + quad * 8 + s * 32];
                acc[nt] = __builtin_amdgcn_mfma_f32_16x16x32_bf16(a, bf, acc[nt], 0, 0, 0);
            }
        }

        const float* bias = layer ? b2 : b1;
        if (layer == 0) {
            __syncthreads();
#pragma unroll
            for (int nt = 0; nt < 8; ++nt) {
                float bv = bias[nt * 16 + l15];
#pragma unroll
                for (int r = 0; r < 4; ++r) {
                    float v = fmaxf(acc[nt][r] + bv, 0.f);
                    hlds[((tile << 6) + w * 16 + quad * 4 + r) * 136 + nt * 16 + l15] = f2bf(v);
                }
            }
        } else {
#pragma unroll
            for (int nt = 0; nt < 8; ++nt) {
                float bv = bias[nt * 16 + l15];
#pragma unroll
                for (int r = 0; r < 4; ++r) {
                    int node = node0 + (tile << 6) + w * 16 + quad * 4 + r;
                    if (node < N)
                        out[(size_t)node * DFEAT + nt * 16 + l15] = acc[nt][r] + bv;
                }
            }
        }
    }
}

// ===========================================================================
// Fallback (tiny ws): atomic scatter + fp32 vector MLP
// ===========================================================================
__global__ void detect_idx_kernel(const int* __restrict__ ei, int* __restrict__ flag) {
    if (threadIdx.x == 0 && blockIdx.x == 0) {
        int orsum = 0;
#pragma unroll
        for (int i = 0; i < 128; ++i) orsum |= ei[2 * i + 1];
        flag[0] = (orsum == 0) ? 1 : 0;
    }
}

__global__ __launch_bounds__(256) void scatter_kernel(
        const float* __restrict__ x, const void* __restrict__ eiv,
        const int* __restrict__ flag, float* __restrict__ agg, int E) {
    unsigned gid = blockIdx.x * 256u + threadIdx.x;
    unsigned e = gid >> 5;
    if (e >= (unsigned)E) return;
    int c = (gid & 31u) * 4;
    int is64 = flag[0];
    int src = load_idx(eiv, is64, (size_t)e);
    int dst = load_idx(eiv, is64, (size_t)E + e);
    float4 v = *(const float4*)&x[(size_t)src * DFEAT + c];
    float* p = &agg[(size_t)dst * DFEAT + c];
    unsafeAtomicAdd(p + 0, v.x);
    unsafeAtomicAdd(p + 1, v.y);
    unsafeAtomicAdd(p + 2, v.z);
    unsafeAtomicAdd(p + 3, v.w);
}

__global__ __launch_bounds__(256) void mlp_kernel(
        const float* __restrict__ xp,
        const float* __restrict__ W1, const float* __restrict__ b1,
        const float* __restrict__ W2, const float* __restrict__ b2,
        const float* __restrict__ epsp, float* __restrict__ out) {
    __shared__ float hs[32][DFEAT];
    __shared__ float Wc[64][DFEAT];

    const int tid = threadIdx.x;
    const int node0 = blockIdx.x * 32;
    const float epsv = 1.0f + epsp[0];

    for (int i = tid; i < 32 * (DFEAT / 4); i += 256) {
        int n = i >> 5;
        int c = (i & 31) * 4;
        size_t off = (size_t)(node0 + n) * DFEAT + c;
        float4 h = *(const float4*)&out[off];
        float4 xv = *(const float4*)&xp[off];
        h.x += epsv * xv.x; h.y += epsv * xv.y;
        h.z += epsv * xv.z; h.w += epsv * xv.w;
        *(float4*)&hs[n][c] = h;
    }

    const int og = (tid & 31) * 4;
    const int ng = (tid >> 5) * 4;

    for (int layer = 0; layer < 2; ++layer) {
        const float* W = layer ? W2 : W1;
        const float* b = layer ? b2 : b1;

        float acc[4][4];
#pragma unroll
        for (int j = 0; j < 4; ++j) {
            float bj = b[og + j];
#pragma unroll
            for (int i = 0; i < 4; ++i) acc[i][j] = bj;
        }

        for (int chunk = 0; chunk < 2; ++chunk) {
            __syncthreads();
            for (int i = tid; i < 64 * (DFEAT / 4); i += 256) {
                int r = i >> 5;
                int c = (i & 31) * 4;
                *(float4*)&Wc[r][c] =
                    *(const float4*)&W[(size_t)(chunk * 64 + r) * DFEAT + c];
            }
            __syncthreads();
            const int kb = chunk * 64;
            for (int k = 0; k < 64; k += 4) {
                float4 h4[4], w4[4];
#pragma unroll
                for (int i = 0; i < 4; ++i)
                    h4[i] = *(const float4*)&hs[ng + i][kb + k];
#pragma unroll
                for (int j = 0; j < 4; ++j)
                    w4[j] = *(const float4*)&Wc[k + j][og];
#pragma unroll
                for (int i = 0; i < 4; ++i) {
                    acc[i][0] += h4[i].x * w4[0].x + h4[i].y * w4[1].x
                               + h4[i].z * w4[2].x + h4[i].w * w4[3].x;
                    acc[i][1] += h4[i].x * w4[0].y + h4[i].y * w4[1].y
                               + h4[i].z * w4[2].y + h4[i].w * w4[3].y;
                    acc[i][2] += h4[i].x * w4[0].z + h4[i].y * w4[1].z
                               + h4[i].z * w4[2].z + h4[i].w * w4[3].z;
                    acc[i][3] += h4[i].x * w4[0].w + h4[i].y * w4[1].w
                               + h4[i].z * w4[2].w + h4[i].w * w4[3].w;
                }
            }
        }
        __syncthreads();

        if (layer == 0) {
#pragma unroll
            for (int i = 0; i < 4; ++i) {
                float4 r;
                r.x = fmaxf(acc[i][0], 0.0f);
                r.y = fmaxf(acc[i][1], 0.0f);
                r.z = fmaxf(acc[i][2], 0.0f);
                r.w = fmaxf(acc[i][3], 0.0f);
                *(float4*)&hs[ng + i][og] = r;
            }
        } else {
#pragma unroll
            for (int i = 0; i < 4; ++i) {
                float4 r;
                r.x = acc[i][0]; r.y = acc[i][1];
                r.z = acc[i][2]; r.w = acc[i][3];
                *(float4*)&out[(size_t)(node0 + ng + i) * DFEAT + og] = r;
            }
        }
    }
}

extern "C" void kernel_launch(void* const* d_in, const int* in_sizes, int n_in,
                              void* d_out, int out_size, void* d_ws, size_t ws_size,
                              hipStream_t stream) {
    const float* x   = (const float*)d_in[0];
    const void*  ei  = d_in[1];
    const float* W1  = (const float*)d_in[2];
    const float* b1  = (const float*)d_in[3];
    const float* W2  = (const float*)d_in[4];
    const float* b2  = (const float*)d_in[5];
    const float* eps = (const float*)d_in[6];
    float* out = (float*)d_out;

    const int N = in_sizes[0] / DFEAT;      // 100000
    const int E = in_sizes[1] / 2;          // 1600000
    const int total4 = N * (DFEAT / 4);     // 3.2M float4s in x
    const int nbkt = (N + 255) >> 8;        // 391 node-range buckets

    // ---- layout: [w1bf][w2bf][xb][ov][ovcnt][gbuf] ----  (~42MB)
    char* p = (char*)d_ws;
    unsigned short* w1bf = (unsigned short*)p;  p += 128 * 128 * 2;
    unsigned short* w2bf = (unsigned short*)p;  p += 128 * 128 * 2;
    unsigned short* xb = (unsigned short*)p;    p += (size_t)N * DFEAT * 2;
    int2* ov = (int2*)p;                        p += (size_t)OVCAP * 8;  // 256KB
    int* ovcnt = (int*)p;                       p += 64;
    unsigned* gbuf = (unsigned*)p;              p += (size_t)nbkt * NA * CELLW * 4; // 16MB
    size_t need = (size_t)(p - (char*)d_ws);

    if (ws_size >= need && nbkt <= MAXBKT) {
        hipMemsetAsync(ovcnt, 0, 64, stream);
        fill_kernel<<<NA, 512, 0, stream>>>(ei, gbuf, ovcnt, ov, E, N, nbkt);
        convert_kernel<<<CVTB, 256, 0, stream>>>(
            W1, W2, w1bf, w2bf, x, xb, total4);
        agg_mlp_kernel<<<nbkt * 2, 512, 0, stream>>>(
            xb, gbuf, ovcnt, ov, eps,
            w1bf, w2bf, b1, b2, out, N);
        return;
    }

    // ---- fallback: atomic scatter + fp32 MLP ----
    int* flag3 = (int*)d_ws;
    detect_idx_kernel<<<1, 64, 0, stream>>>((const int*)ei, flag3);
    hipMemsetAsync(d_out, 0, (size_t)out_size * sizeof(float), stream);
    unsigned total = (unsigned)E * 32u;
    scatter_kernel<<<(total + 255u) / 256u, 256, 0, stream>>>(x, ei, flag3, out, E);
    mlp_kernel<<<N / 32, 256, 0, stream>>>(x, W1, b1, W2, b2, eps, out);
}